// Round 1
// baseline (402.979 us; speedup 1.0000x reference)
//
#include <hip/hip_runtime.h>
#include <math.h>

#define NL 4
#define NBATCH 16384
#define NS 5
#define ND 6
#define NH 2
#define NHD 3
#define NFF 2048
#define EPSV 1e-5f

#define ITEMS 64
#define NWAVE 8
#define TPB (NWAVE * 64)      // 512
#define JPW (NFF / NWAVE)     // 256
#define ROW (NS * ND)         // 30 floats of state per item
#define NVAL (ITEMS * ROW)    // 1920 state floats per block

// packed FFN weights: per (layer, j): [W1row(6), b1(1), W2col(6), pad(3)] = 16 floats
__device__ __align__(16) float g_pack[NL * NFF * 16];

__global__ void pack_kernel(const float* __restrict__ W1,
                            const float* __restrict__ b1,
                            const float* __restrict__ W2) {
    int idx = blockIdx.x * 256 + threadIdx.x;  // l*NFF + j
    if (idx >= NL * NFF) return;
    int l = idx / NFF, j = idx - l * NFF;
    float o[16];
#pragma unroll
    for (int d = 0; d < ND; ++d) o[d] = W1[(size_t)(l * NFF + j) * ND + d];
    o[6] = b1[l * NFF + j];
#pragma unroll
    for (int d = 0; d < ND; ++d) o[7 + d] = W2[((size_t)l * ND + d) * NFF + j];
    o[13] = o[14] = o[15] = 0.f;
#pragma unroll
    for (int k = 0; k < 4; ++k)
        ((float4*)&g_pack[(size_t)idx * 16])[k] = ((float4*)o)[k];
}

__global__ __launch_bounds__(TPB, 2) void encoder_kernel(
    const float* __restrict__ xin,
    const float* __restrict__ Wq, const float* __restrict__ bq,
    const float* __restrict__ Wk, const float* __restrict__ bk,
    const float* __restrict__ Wv, const float* __restrict__ bv,
    const float* __restrict__ Wo, const float* __restrict__ bo,
    const float* __restrict__ b2,
    const float* __restrict__ g1, const float* __restrict__ be1,
    const float* __restrict__ g2, const float* __restrict__ be2,
    const float* __restrict__ Wfc, const float* __restrict__ bfc,
    float* __restrict__ out) {
    __shared__ float xs[NVAL];                 // 7.5 KB persistent x state
    __shared__ float kvs[ITEMS * NS * 2 * ND]; // 15 KB k,v per (item,token)
    __shared__ float party[4 * NVAL];          // 30.7 KB ffn partials (2-stage reduce)

    const int tid = threadIdx.x;
    const int base = blockIdx.x * ITEMS;

    // load x block: 1920 floats = 480 float4
    if (tid < NVAL / 4)
        ((float4*)xs)[tid] = ((const float4*)(xin + (size_t)base * ROW))[tid];
    __syncthreads();

    const bool act = tid < ITEMS * NS;  // 320 attention threads: (item, token)
    const int ai = tid / NS;
    const int at = tid - ai * NS;

    const int item = tid & 63;                                   // ffn lane = item
    const int wp = __builtin_amdgcn_readfirstlane(tid >> 6);     // ffn wave = FF partition

    for (int l = 0; l < NL; ++l) {
        // ---------------- attention: qkv ----------------
        float xr[ND], qv[ND];
        if (act) {
#pragma unroll
            for (int d = 0; d < ND; ++d) xr[d] = xs[(ai * NS + at) * ND + d];
#pragma unroll
            for (int d = 0; d < ND; ++d) {
                float aq = bq[l * ND + d], ak = bk[l * ND + d], av = bv[l * ND + d];
#pragma unroll
                for (int e = 0; e < ND; ++e) {
                    aq += Wq[(l * ND + d) * ND + e] * xr[e];
                    ak += Wk[(l * ND + d) * ND + e] * xr[e];
                    av += Wv[(l * ND + d) * ND + e] * xr[e];
                }
                qv[d] = aq;
                kvs[(ai * NS + at) * 2 * ND + d] = ak;
                kvs[(ai * NS + at) * 2 * ND + ND + d] = av;
            }
        }
        __syncthreads();
        // ---------------- attention: scores/ctx/outproj/LN1 ----------------
        if (act) {
            const float scale = 0.57735026919f;  // 1/sqrt(HD)
            float ctx[ND];
#pragma unroll
            for (int h = 0; h < NH; ++h) {
                float sc[NS];
                float mx = -1e30f;
#pragma unroll
                for (int u = 0; u < NS; ++u) {
                    float s = 0.f;
#pragma unroll
                    for (int d = 0; d < NHD; ++d)
                        s += qv[h * NHD + d] * kvs[(ai * NS + u) * 2 * ND + h * NHD + d];
                    s *= scale;
                    sc[u] = s;
                    mx = fmaxf(mx, s);
                }
                float sum = 0.f;
#pragma unroll
                for (int u = 0; u < NS; ++u) {
                    sc[u] = __expf(sc[u] - mx);
                    sum += sc[u];
                }
                float inv = 1.f / sum;
#pragma unroll
                for (int d = 0; d < NHD; ++d) {
                    float c = 0.f;
#pragma unroll
                    for (int u = 0; u < NS; ++u)
                        c += sc[u] * kvs[(ai * NS + u) * 2 * ND + ND + h * NHD + d];
                    ctx[h * NHD + d] = c * inv;
                }
            }
            float yr[ND];
#pragma unroll
            for (int d = 0; d < ND; ++d) {
                float a = bo[l * ND + d];
#pragma unroll
                for (int e = 0; e < ND; ++e) a += Wo[(l * ND + d) * ND + e] * ctx[e];
                yr[d] = a + xr[d];
            }
            float m = 0.f;
#pragma unroll
            for (int d = 0; d < ND; ++d) m += yr[d];
            m *= (1.f / ND);
            float va = 0.f;
#pragma unroll
            for (int d = 0; d < ND; ++d) {
                float dv = yr[d] - m;
                va += dv * dv;
            }
            va *= (1.f / ND);
            float r = rsqrtf(va + EPSV);
#pragma unroll
            for (int d = 0; d < ND; ++d)
                xs[(ai * NS + at) * ND + d] =
                    (yr[d] - m) * r * g1[l * ND + d] + be1[l * ND + d];
        }
        __syncthreads();
        // ---------------- FFN: all 512 threads ----------------
        float xl[NS][ND];
#pragma unroll
        for (int t = 0; t < NS; ++t)
#pragma unroll
            for (int d = 0; d < ND; ++d) xl[t][d] = xs[(item * NS + t) * ND + d];
        float accv[NS][ND] = {};
        const float4* wbase = ((const float4*)g_pack) + (size_t)(l * NFF + wp * JPW) * 4;
#pragma unroll 2
        for (int jj = 0; jj < JPW; ++jj) {
            float4 wa = wbase[jj * 4 + 0];  // W1row[0..3]
            float4 wb = wbase[jj * 4 + 1];  // W1row[4,5], b1, W2col[0]
            float4 wc = wbase[jj * 4 + 2];  // W2col[1..4]
            float4 wd = wbase[jj * 4 + 3];  // W2col[5], pad
#pragma unroll
            for (int t = 0; t < NS; ++t) {
                float hs = wb.z;
                hs += wa.x * xl[t][0];
                hs += wa.y * xl[t][1];
                hs += wa.z * xl[t][2];
                hs += wa.w * xl[t][3];
                hs += wb.x * xl[t][4];
                hs += wb.y * xl[t][5];
                float hr = fmaxf(hs, 0.f);
                accv[t][0] += hr * wb.w;
                accv[t][1] += hr * wc.x;
                accv[t][2] += hr * wc.y;
                accv[t][3] += hr * wc.z;
                accv[t][4] += hr * wc.w;
                accv[t][5] += hr * wd.x;
            }
        }
        // two-stage partial reduce: waves 0-3 write, waves 4-7 accumulate
        if (wp < 4) {
#pragma unroll
            for (int t = 0; t < NS; ++t)
#pragma unroll
                for (int d = 0; d < ND; ++d)
                    party[(wp * ITEMS + item) * ROW + t * ND + d] = accv[t][d];
        }
        __syncthreads();
        if (wp >= 4) {
#pragma unroll
            for (int t = 0; t < NS; ++t)
#pragma unroll
                for (int d = 0; d < ND; ++d)
                    party[((wp - 4) * ITEMS + item) * ROW + t * ND + d] += accv[t][d];
        }
        __syncthreads();
        // final reduce of 4 partials, in place into party[0..NVAL)
        if (tid < NVAL / 4) {
            float4* pf4 = (float4*)party;
            float4 s = pf4[tid];
#pragma unroll
            for (int p = 1; p < 4; ++p) {
                float4 v = pf4[p * (NVAL / 4) + tid];
                s.x += v.x;
                s.y += v.y;
                s.z += v.z;
                s.w += v.w;
            }
            pf4[tid] = s;
        }
        __syncthreads();
        // ---------------- residual + LN2 ----------------
        if (act) {
            int rb = (ai * NS + at) * ND;
            float yr[ND];
#pragma unroll
            for (int d = 0; d < ND; ++d)
                yr[d] = xs[rb + d] + party[rb + d] + b2[l * ND + d];
            float m = 0.f;
#pragma unroll
            for (int d = 0; d < ND; ++d) m += yr[d];
            m *= (1.f / ND);
            float va = 0.f;
#pragma unroll
            for (int d = 0; d < ND; ++d) {
                float dv = yr[d] - m;
                va += dv * dv;
            }
            va *= (1.f / ND);
            float r = rsqrtf(va + EPSV);
#pragma unroll
            for (int d = 0; d < ND; ++d)
                xs[rb + d] = (yr[d] - m) * r * g2[l * ND + d] + be2[l * ND + d];
        }
        __syncthreads();
    }
    // ---------------- classification head + softmax ----------------
    if (tid < ITEMS) {
        float l0 = bfc[0], l1 = bfc[1];
#pragma unroll
        for (int v = 0; v < ROW; ++v) {
            float xv = xs[tid * ROW + v];
            l0 += Wfc[v] * xv;
            l1 += Wfc[ROW + v] * xv;
        }
        float mx = fmaxf(l0, l1);
        float e0 = __expf(l0 - mx), e1 = __expf(l1 - mx);
        float inv = 1.f / (e0 + e1);
        out[(size_t)(base + tid) * 2 + 0] = e0 * inv;
        out[(size_t)(base + tid) * 2 + 1] = e1 * inv;
    }
}

extern "C" void kernel_launch(void* const* d_in, const int* in_sizes, int n_in,
                              void* d_out, int out_size, void* d_ws, size_t ws_size,
                              hipStream_t stream) {
    (void)in_sizes; (void)n_in; (void)d_ws; (void)ws_size; (void)out_size;
    const float* x = (const float*)d_in[0];
    const float* Wq = (const float*)d_in[1];
    const float* bq = (const float*)d_in[2];
    const float* Wk = (const float*)d_in[3];
    const float* bk = (const float*)d_in[4];
    const float* Wv = (const float*)d_in[5];
    const float* bv = (const float*)d_in[6];
    const float* Wo = (const float*)d_in[7];
    const float* bo = (const float*)d_in[8];
    const float* W1 = (const float*)d_in[9];
    const float* b1 = (const float*)d_in[10];
    const float* W2 = (const float*)d_in[11];
    const float* b2 = (const float*)d_in[12];
    const float* g1 = (const float*)d_in[13];
    const float* be1 = (const float*)d_in[14];
    const float* g2 = (const float*)d_in[15];
    const float* be2 = (const float*)d_in[16];
    const float* Wfc = (const float*)d_in[17];
    const float* bfc = (const float*)d_in[18];
    float* out = (float*)d_out;

    hipLaunchKernelGGL(pack_kernel, dim3((NL * NFF + 255) / 256), dim3(256), 0, stream,
                       W1, b1, W2);
    hipLaunchKernelGGL(encoder_kernel, dim3(NBATCH / ITEMS), dim3(TPB), 0, stream,
                       x, Wq, bq, Wk, bk, Wv, bv, Wo, bo, b2, g1, be1, g2, be2,
                       Wfc, bfc, out);
}

// Round 3
// 196.911 us; speedup vs baseline: 2.0465x; 2.0465x over previous
//
#include <hip/hip_runtime.h>
#include <math.h>

#define NL 4
#define NBATCH 16384
#define NS 5
#define ND 6
#define NH 2
#define NHD 3
#define NFF 2048
#define EPSV 1e-5f

#define ITEMS 32               // items per block
#define NWAVE 8
#define TPB (NWAVE * 64)       // 512 threads
#define NFID 16                // ffn partitions per block (tid>>5)
#define JPAIRS (NFF / 2)       // 1024 j-pairs
#define JPF (JPAIRS / NFID)    // 64 j-pairs per partition
#define ROW (NS * ND)          // 30 floats of state per item
#define NVAL (ITEMS * ROW)     // 960 state floats per block

typedef _Float16 h2_t __attribute__((ext_vector_type(2)));

__device__ inline h2_t as_h2(unsigned int u) {
    union { unsigned int u; h2_t h; } x; x.u = u; return x.h;
}
__device__ inline float as_f(unsigned int u) {
    union { unsigned int u; float f; } x; x.u = u; return x.f;
}
__device__ inline h2_t pk(float a, float b) {
#if __has_builtin(__builtin_amdgcn_cvt_pkrtz)
    union {
        __fp16 v __attribute__((ext_vector_type(2)));
        h2_t h;
    } x;
    x.v = __builtin_amdgcn_cvt_pkrtz(a, b);
    return x.h;
#else
    h2_t r; r.x = (_Float16)a; r.y = (_Float16)b; return r;
#endif
}
__device__ inline float fdot2f(h2_t a, h2_t b, float c) {
#if __has_builtin(__builtin_amdgcn_fdot2)
    return __builtin_amdgcn_fdot2(a, b, c, false);
#else
    return c + (float)a.x * (float)b.x + (float)a.y * (float)b.y;
#endif
}

// packed FFN weights per (layer, jpair): 16 dwords (64 B):
// [0..2] w1(j0) d-pairs, [3..5] w1(j1) d-pairs, [6] b1(j0) f32, [7] b1(j1) f32,
// [8..13] w2 cross-pair (W2[d][j0],W2[d][j1]) for d=0..5, [14..15] pad
__device__ __align__(16) unsigned int g_pack[NL * JPAIRS * 16];

__device__ inline unsigned int packh(float a, float b) {
    union { _Float16 h[2]; unsigned int u; } x;
    x.h[0] = (_Float16)a; x.h[1] = (_Float16)b; return x.u;
}

__global__ void pack_kernel(const float* __restrict__ W1,
                            const float* __restrict__ b1,
                            const float* __restrict__ W2) {
    int idx = blockIdx.x * 256 + threadIdx.x;  // l*JPAIRS + jp
    if (idx >= NL * JPAIRS) return;
    int l = idx >> 10, jp = idx & (JPAIRS - 1);
    int j0 = 2 * jp, j1 = j0 + 1;
    unsigned int dw[16];
#pragma unroll
    for (int p = 0; p < 3; ++p) {
        dw[p]     = packh(W1[(size_t)(l * NFF + j0) * ND + 2 * p],
                          W1[(size_t)(l * NFF + j0) * ND + 2 * p + 1]);
        dw[3 + p] = packh(W1[(size_t)(l * NFF + j1) * ND + 2 * p],
                          W1[(size_t)(l * NFF + j1) * ND + 2 * p + 1]);
    }
    dw[6] = __float_as_uint(b1[l * NFF + j0]);
    dw[7] = __float_as_uint(b1[l * NFF + j1]);
#pragma unroll
    for (int d = 0; d < ND; ++d)
        dw[8 + d] = packh(W2[((size_t)l * ND + d) * NFF + j0],
                          W2[((size_t)l * ND + d) * NFF + j1]);
    dw[14] = dw[15] = 0;
#pragma unroll
    for (int k = 0; k < 4; ++k)
        ((uint4*)&g_pack[(size_t)idx * 16])[k] = ((uint4*)dw)[k];
}

__global__ __launch_bounds__(TPB, 4) void encoder_kernel(
    const float* __restrict__ xin,
    const float* __restrict__ Wq, const float* __restrict__ bq,
    const float* __restrict__ Wk, const float* __restrict__ bk,
    const float* __restrict__ Wv, const float* __restrict__ bv,
    const float* __restrict__ Wo, const float* __restrict__ bo,
    const float* __restrict__ b2,
    const float* __restrict__ g1, const float* __restrict__ be1,
    const float* __restrict__ g2, const float* __restrict__ be2,
    const float* __restrict__ Wfc, const float* __restrict__ bfc,
    float* __restrict__ out) {
    __shared__ float xs[NVAL];                  // 3.84 KB persistent x state
    __shared__ float kvs[ITEMS * NS * 2 * ND];  // 7.68 KB k,v
    __shared__ float party[8 * NVAL];           // 30.72 KB ffn partials

    const int tid = threadIdx.x;
    const int base = blockIdx.x * ITEMS;

    if (tid < NVAL / 4)
        ((float4*)xs)[tid] = ((const float4*)(xin + (size_t)base * ROW))[tid];
    __syncthreads();

    const bool act = tid < ITEMS * NS;  // 160 attention threads: (item, token)
    const int ai = tid / NS;
    const int at = tid - ai * NS;

    const int item = tid & 31;   // ffn lane -> item
    const int fid = tid >> 5;    // ffn partition 0..15

    for (int l = 0; l < NL; ++l) {
        // ---------------- attention: qkv ----------------
        float xr[ND], qv[ND];
        if (act) {
#pragma unroll
            for (int d = 0; d < ND; ++d) xr[d] = xs[(ai * NS + at) * ND + d];
#pragma unroll
            for (int d = 0; d < ND; ++d) {
                float aq = bq[l * ND + d], ak = bk[l * ND + d], av = bv[l * ND + d];
#pragma unroll
                for (int e = 0; e < ND; ++e) {
                    aq += Wq[(l * ND + d) * ND + e] * xr[e];
                    ak += Wk[(l * ND + d) * ND + e] * xr[e];
                    av += Wv[(l * ND + d) * ND + e] * xr[e];
                }
                qv[d] = aq;
                kvs[(ai * NS + at) * 2 * ND + d] = ak;
                kvs[(ai * NS + at) * 2 * ND + ND + d] = av;
            }
        }
        __syncthreads();
        // ---------------- attention: scores/ctx/outproj/LN1 ----------------
        if (act) {
            const float scale = 0.57735026919f;  // 1/sqrt(HD)
            float ctx[ND];
#pragma unroll
            for (int h = 0; h < NH; ++h) {
                float sc[NS];
                float mx = -1e30f;
#pragma unroll
                for (int u = 0; u < NS; ++u) {
                    float s = 0.f;
#pragma unroll
                    for (int d = 0; d < NHD; ++d)
                        s += qv[h * NHD + d] * kvs[(ai * NS + u) * 2 * ND + h * NHD + d];
                    s *= scale;
                    sc[u] = s;
                    mx = fmaxf(mx, s);
                }
                float sum = 0.f;
#pragma unroll
                for (int u = 0; u < NS; ++u) {
                    sc[u] = __expf(sc[u] - mx);
                    sum += sc[u];
                }
                float inv = 1.f / sum;
#pragma unroll
                for (int d = 0; d < NHD; ++d) {
                    float c = 0.f;
#pragma unroll
                    for (int u = 0; u < NS; ++u)
                        c += sc[u] * kvs[(ai * NS + u) * 2 * ND + ND + h * NHD + d];
                    ctx[h * NHD + d] = c * inv;
                }
            }
            float yr[ND];
#pragma unroll
            for (int d = 0; d < ND; ++d) {
                float a = bo[l * ND + d];
#pragma unroll
                for (int e = 0; e < ND; ++e) a += Wo[(l * ND + d) * ND + e] * ctx[e];
                yr[d] = a + xr[d];
            }
            float m = 0.f;
#pragma unroll
            for (int d = 0; d < ND; ++d) m += yr[d];
            m *= (1.f / ND);
            float va = 0.f;
#pragma unroll
            for (int d = 0; d < ND; ++d) { float dv = yr[d] - m; va += dv * dv; }
            va *= (1.f / ND);
            float r = rsqrtf(va + EPSV);
#pragma unroll
            for (int d = 0; d < ND; ++d)
                xs[(ai * NS + at) * ND + d] =
                    (yr[d] - m) * r * g1[l * ND + d] + be1[l * ND + d];
        }
        __syncthreads();
        // ---------------- FFN: all 512 threads, f16 dot2 ----------------
        h2_t xh[NS][3];
#pragma unroll
        for (int t = 0; t < NS; ++t)
#pragma unroll
            for (int p = 0; p < 3; ++p) {
                float2 v = *(const float2*)&xs[item * ROW + t * ND + 2 * p];
                xh[t][p] = pk(v.x, v.y);
            }
        float acc[NS][ND] = {};
        const unsigned int* wptr = g_pack + (size_t)(l * JPAIRS + fid * JPF) * 16;
#pragma unroll 2
        for (int jj = 0; jj < JPF; ++jj) {
            const uint4* wr = (const uint4*)(wptr + jj * 16);
            uint4 wa = wr[0], wb = wr[1], wc = wr[2], wd = wr[3];
#pragma unroll
            for (int t = 0; t < NS; ++t) {
                float s0 = as_f(wb.z), s1 = as_f(wb.w);
                s0 = fdot2f(xh[t][0], as_h2(wa.x), s0);
                s0 = fdot2f(xh[t][1], as_h2(wa.y), s0);
                s0 = fdot2f(xh[t][2], as_h2(wa.z), s0);
                s1 = fdot2f(xh[t][0], as_h2(wa.w), s1);
                s1 = fdot2f(xh[t][1], as_h2(wb.x), s1);
                s1 = fdot2f(xh[t][2], as_h2(wb.y), s1);
                h2_t hp = pk(fmaxf(s0, 0.f), fmaxf(s1, 0.f));
                acc[t][0] = fdot2f(hp, as_h2(wc.x), acc[t][0]);
                acc[t][1] = fdot2f(hp, as_h2(wc.y), acc[t][1]);
                acc[t][2] = fdot2f(hp, as_h2(wc.z), acc[t][2]);
                acc[t][3] = fdot2f(hp, as_h2(wc.w), acc[t][3]);
                acc[t][4] = fdot2f(hp, as_h2(wd.x), acc[t][4]);
                acc[t][5] = fdot2f(hp, as_h2(wd.y), acc[t][5]);
            }
        }
        // two-stage partial reduce: fid 0-7 write, fid 8-15 accumulate
        if (fid < 8) {
#pragma unroll
            for (int t = 0; t < NS; ++t)
#pragma unroll
                for (int d = 0; d < ND; ++d)
                    party[(fid * ITEMS + item) * ROW + t * ND + d] = acc[t][d];
        }
        __syncthreads();
        if (fid >= 8) {
#pragma unroll
            for (int t = 0; t < NS; ++t)
#pragma unroll
                for (int d = 0; d < ND; ++d)
                    party[((fid - 8) * ITEMS + item) * ROW + t * ND + d] += acc[t][d];
        }
        __syncthreads();
        // final reduce of 8 partials into party[0..NVAL)
        if (tid < NVAL / 4) {
            float4* pf4 = (float4*)party;
            float4 s = pf4[tid];
#pragma unroll
            for (int p = 1; p < 8; ++p) {
                float4 v = pf4[p * (NVAL / 4) + tid];
                s.x += v.x; s.y += v.y; s.z += v.z; s.w += v.w;
            }
            pf4[tid] = s;
        }
        __syncthreads();
        // ---------------- residual + LN2 ----------------
        if (act) {
            int rb = (ai * NS + at) * ND;
            float yr[ND];
#pragma unroll
            for (int d = 0; d < ND; ++d)
                yr[d] = xs[rb + d] + party[rb + d] + b2[l * ND + d];
            float m = 0.f;
#pragma unroll
            for (int d = 0; d < ND; ++d) m += yr[d];
            m *= (1.f / ND);
            float va = 0.f;
#pragma unroll
            for (int d = 0; d < ND; ++d) { float dv = yr[d] - m; va += dv * dv; }
            va *= (1.f / ND);
            float r = rsqrtf(va + EPSV);
#pragma unroll
            for (int d = 0; d < ND; ++d)
                xs[rb + d] = (yr[d] - m) * r * g2[l * ND + d] + be2[l * ND + d];
        }
        __syncthreads();
    }
    // ---------------- classification head + softmax ----------------
    if (tid < ITEMS) {
        float l0 = bfc[0], l1 = bfc[1];
#pragma unroll
        for (int v = 0; v < ROW; ++v) {
            float xv = xs[tid * ROW + v];
            l0 += Wfc[v] * xv;
            l1 += Wfc[ROW + v] * xv;
        }
        float mx = fmaxf(l0, l1);
        float e0 = __expf(l0 - mx), e1 = __expf(l1 - mx);
        float inv = 1.f / (e0 + e1);
        out[(size_t)(base + tid) * 2 + 0] = e0 * inv;
        out[(size_t)(base + tid) * 2 + 1] = e1 * inv;
    }
}

extern "C" void kernel_launch(void* const* d_in, const int* in_sizes, int n_in,
                              void* d_out, int out_size, void* d_ws, size_t ws_size,
                              hipStream_t stream) {
    (void)in_sizes; (void)n_in; (void)d_ws; (void)ws_size; (void)out_size;
    const float* x = (const float*)d_in[0];
    const float* Wq = (const float*)d_in[1];
    const float* bq = (const float*)d_in[2];
    const float* Wk = (const float*)d_in[3];
    const float* bk = (const float*)d_in[4];
    const float* Wv = (const float*)d_in[5];
    const float* bv = (const float*)d_in[6];
    const float* Wo = (const float*)d_in[7];
    const float* bo = (const float*)d_in[8];
    const float* W1 = (const float*)d_in[9];
    const float* b1 = (const float*)d_in[10];
    const float* W2 = (const float*)d_in[11];
    const float* b2 = (const float*)d_in[12];
    const float* g1 = (const float*)d_in[13];
    const float* be1 = (const float*)d_in[14];
    const float* g2 = (const float*)d_in[15];
    const float* be2 = (const float*)d_in[16];
    const float* Wfc = (const float*)d_in[17];
    const float* bfc = (const float*)d_in[18];
    float* out = (float*)d_out;

    hipLaunchKernelGGL(pack_kernel, dim3((NL * JPAIRS + 255) / 256), dim3(256), 0,
                       stream, W1, b1, W2);
    hipLaunchKernelGGL(encoder_kernel, dim3(NBATCH / ITEMS), dim3(TPB), 0, stream,
                       x, Wq, bq, Wk, bk, Wv, bv, Wo, bo, b2, g1, be1, g2, be2,
                       Wfc, bfc, out);
}

// Round 4
// 99.605 us; speedup vs baseline: 4.0458x; 1.9769x over previous
//
#include <hip/hip_runtime.h>
#include <math.h>

#define NL 4
#define NBATCH 16384
#define NS 5
#define ND 6
#define NH 2
#define NHD 3
#define NFF 2048
#define EPSV 1e-5f

#define ITEMS 64               // items per block
#define TPB 512                // 8 waves
#define NJT 128                // j-tiles of 16 per layer
#define ROW (NS * ND)          // 30
#define NVAL (ITEMS * ROW)     // 1920

typedef __fp16 v4h __attribute__((ext_vector_type(4)));
typedef __fp16 v2h __attribute__((ext_vector_type(2)));
typedef float f32x4 __attribute__((ext_vector_type(4)));

union HU { uint2 u; v4h h; __fp16 f[4]; };

__device__ inline unsigned pk_u32(float a, float b) {
    union { v2h h; unsigned u; } x;
    x.h = __builtin_amdgcn_cvt_pkrtz(a, b);
    return x.u;
}

// Prepacked MFMA A-fragments (f16) + b1 C-fragments (f32).
// A-frag layout for v_mfma_f32_16x16x16f16: lane l holds A[row=l&15][k=4*(l>>4)+e]
__device__ __align__(8) uint2 W1T[NL * NJT * 64];    // GEMM1 A: W1[j=row][k=d(pad16)]
__device__ __align__(8) uint2 W2T[NL * NJT * 64];    // GEMM2 A: W2[d=row(pad16)][k=j]
__device__ __align__(16) f32x4 B1T[NL * NJT * 4];    // b1 per (jt, lanegroup): b1[jt*16+4g+i]

__global__ void pack_kernel(const float* __restrict__ W1,
                            const float* __restrict__ b1,
                            const float* __restrict__ W2) {
    int idx = blockIdx.x * 256 + threadIdx.x;
    if (idx < NL * NJT * 64) {              // W1T
        int lane = idx & 63, jt = (idx >> 6) & 127, l = idx >> 13;
        int cc = lane & 15, g = lane >> 4;
        HU o; o.u = make_uint2(0u, 0u);
        if (g < 2) {
            int j = jt * 16 + cc;
#pragma unroll
            for (int e = 0; e < 4; ++e) {
                int k = 4 * g + e;
                o.f[e] = (k < ND) ? (__fp16)W1[(size_t)(l * NFF + j) * ND + k]
                                  : (__fp16)0.f;
            }
        }
        W1T[idx] = o.u;
    } else if (idx < 2 * NL * NJT * 64) {   // W2T
        int t = idx - NL * NJT * 64;
        int lane = t & 63, jt = (t >> 6) & 127, l = t >> 13;
        int d = lane & 15, g = lane >> 4;
        HU o; o.u = make_uint2(0u, 0u);
        if (d < ND) {
#pragma unroll
            for (int e = 0; e < 4; ++e) {
                int j = jt * 16 + 4 * g + e;
                o.f[e] = (__fp16)W2[(size_t)(l * ND + d) * NFF + j];
            }
        }
        W2T[t] = o.u;
    } else if (idx < 2 * NL * NJT * 64 + NL * NJT * 4) {  // B1T
        int t = idx - 2 * NL * NJT * 64;    // ((l*128+jt)*4+g)
        int g = t & 3, jt = (t >> 2) & 127, l = t >> 9;
        f32x4 v;
        v.x = b1[l * NFF + jt * 16 + 4 * g + 0];
        v.y = b1[l * NFF + jt * 16 + 4 * g + 1];
        v.z = b1[l * NFF + jt * 16 + 4 * g + 2];
        v.w = b1[l * NFF + jt * 16 + 4 * g + 3];
        B1T[t] = v;
    }
}

__global__ __launch_bounds__(TPB, 2) void encoder_kernel(
    const float* __restrict__ xin,
    const float* __restrict__ Wq, const float* __restrict__ bq,
    const float* __restrict__ Wk, const float* __restrict__ bk,
    const float* __restrict__ Wv, const float* __restrict__ bv,
    const float* __restrict__ Wo, const float* __restrict__ bo,
    const float* __restrict__ b2,
    const float* __restrict__ g1, const float* __restrict__ be1,
    const float* __restrict__ g2, const float* __restrict__ be2,
    const float* __restrict__ Wfc, const float* __restrict__ bfc,
    float* __restrict__ out) {
    __shared__ float xs[NVAL];                   // 7.68 KB x state (f32 rows of 6)
    __shared__ float kvs[ITEMS * NS * 2 * ND];   // 15.36 KB k,v
    __shared__ float ybuf[2 * 4 * 5 * 64 * 4];   // 40.96 KB y fragments (jh, ig, mt, lane, 4)

    const int tid = threadIdx.x;
    const int base = blockIdx.x * ITEMS;

    if (tid < NVAL / 4)
        ((float4*)xs)[tid] = ((const float4*)(xin + (size_t)base * ROW))[tid];
    __syncthreads();

    const bool act = tid < ITEMS * NS;  // 320 attention threads: (item, token)
    const int ai = tid / NS;
    const int at = tid - ai * NS;

    // FFN wave roles: wave w: item-group ig (16 items = 5 M-tiles), j-half jh
    const int lane = tid & 63;
    const int w = tid >> 6;
    const int ig = w & 3, jh = w >> 2;
    const int c16 = lane & 15, g = lane >> 4;

    for (int l = 0; l < NL; ++l) {
        // ---------------- attention: qkv ----------------
        float xr[ND], qv[ND];
        if (act) {
#pragma unroll
            for (int d = 0; d < ND; ++d) xr[d] = xs[(ai * NS + at) * ND + d];
#pragma unroll
            for (int d = 0; d < ND; ++d) {
                float aq = bq[l * ND + d], ak = bk[l * ND + d], av = bv[l * ND + d];
#pragma unroll
                for (int e = 0; e < ND; ++e) {
                    aq += Wq[(l * ND + d) * ND + e] * xr[e];
                    ak += Wk[(l * ND + d) * ND + e] * xr[e];
                    av += Wv[(l * ND + d) * ND + e] * xr[e];
                }
                qv[d] = aq;
                kvs[(ai * NS + at) * 2 * ND + d] = ak;
                kvs[(ai * NS + at) * 2 * ND + ND + d] = av;
            }
        }
        __syncthreads();
        // ---------------- attention: scores/ctx/outproj/LN1 ----------------
        if (act) {
            const float scale = 0.57735026919f;  // 1/sqrt(HD)
            float ctx[ND];
#pragma unroll
            for (int h = 0; h < NH; ++h) {
                float sc[NS];
                float mx = -1e30f;
#pragma unroll
                for (int u = 0; u < NS; ++u) {
                    float s = 0.f;
#pragma unroll
                    for (int d = 0; d < NHD; ++d)
                        s += qv[h * NHD + d] * kvs[(ai * NS + u) * 2 * ND + h * NHD + d];
                    s *= scale;
                    sc[u] = s;
                    mx = fmaxf(mx, s);
                }
                float sum = 0.f;
#pragma unroll
                for (int u = 0; u < NS; ++u) {
                    sc[u] = __expf(sc[u] - mx);
                    sum += sc[u];
                }
                float inv = 1.f / sum;
#pragma unroll
                for (int d = 0; d < NHD; ++d) {
                    float cx = 0.f;
#pragma unroll
                    for (int u = 0; u < NS; ++u)
                        cx += sc[u] * kvs[(ai * NS + u) * 2 * ND + ND + h * NHD + d];
                    ctx[h * NHD + d] = cx * inv;
                }
            }
            float yr[ND];
#pragma unroll
            for (int d = 0; d < ND; ++d) {
                float a = bo[l * ND + d];
#pragma unroll
                for (int e = 0; e < ND; ++e) a += Wo[(l * ND + d) * ND + e] * ctx[e];
                yr[d] = a + xr[d];
            }
            float m = 0.f;
#pragma unroll
            for (int d = 0; d < ND; ++d) m += yr[d];
            m *= (1.f / ND);
            float va = 0.f;
#pragma unroll
            for (int d = 0; d < ND; ++d) { float dv = yr[d] - m; va += dv * dv; }
            va *= (1.f / ND);
            float r = rsqrtf(va + EPSV);
#pragma unroll
            for (int d = 0; d < ND; ++d)
                xs[(ai * NS + at) * ND + d] =
                    (yr[d] - m) * r * g1[l * ND + d] + be1[l * ND + d];
        }
        __syncthreads();
        // ---------------- FFN: MFMA, all 8 waves ----------------
        // Build X B-frags per M-tile: lane holds X^T[k=4g+e][m=c16] (k = d, pad 6->16)
        v4h xb[5];
#pragma unroll
        for (int mt = 0; mt < 5; ++mt) {
            HU u; u.u = make_uint2(0u, 0u);
            int row = ig * 80 + mt * 16 + c16;
            if (g == 0) {
                float2 a = *(const float2*)&xs[row * 6];
                float2 b = *(const float2*)&xs[row * 6 + 2];
                u.u.x = pk_u32(a.x, a.y);
                u.u.y = pk_u32(b.x, b.y);
            } else if (g == 1) {
                float2 a = *(const float2*)&xs[row * 6 + 4];
                u.u.x = pk_u32(a.x, a.y);
            }
            xb[mt] = u.h;
        }
        f32x4 y0 = {0.f, 0.f, 0.f, 0.f}, y1 = y0, y2 = y0, y3 = y0, y4 = y0;
        const uint2* w1p = W1T + ((size_t)(l * NJT + jh * 64)) * 64 + lane;
        const uint2* w2p = W2T + ((size_t)(l * NJT + jh * 64)) * 64 + lane;
        const f32x4* b1p = B1T + ((size_t)(l * NJT + jh * 64)) * 4 + g;
#pragma unroll 2
        for (int jt = 0; jt < 64; ++jt) {
            HU a1; a1.u = w1p[jt * 64];
            HU a2; a2.u = w2p[jt * 64];
            f32x4 bb = b1p[jt * 4];
#define FFN_STEP(YREG, XB)                                                      \
            {                                                                   \
                f32x4 hh = __builtin_amdgcn_mfma_f32_16x16x16f16(               \
                    a1.h, (XB), bb, 0, 0, 0);                                   \
                HU hb;                                                          \
                hb.u.x = pk_u32(fmaxf(hh.x, 0.f), fmaxf(hh.y, 0.f));            \
                hb.u.y = pk_u32(fmaxf(hh.z, 0.f), fmaxf(hh.w, 0.f));            \
                YREG = __builtin_amdgcn_mfma_f32_16x16x16f16(                   \
                    a2.h, hb.h, YREG, 0, 0, 0);                                 \
            }
            FFN_STEP(y0, xb[0])
            FFN_STEP(y1, xb[1])
            FFN_STEP(y2, xb[2])
            FFN_STEP(y3, xb[3])
            FFN_STEP(y4, xb[4])
#undef FFN_STEP
        }
        // write y fragments: ybuf[jh][ig][mt][lane][0..3]
        {
            f32x4* yb = (f32x4*)ybuf;
            int sb = ((jh * 4 + ig) * 5) * 64 + lane;
            yb[sb + 0 * 64] = y0;
            yb[sb + 1 * 64] = y1;
            yb[sb + 2 * 64] = y2;
            yb[sb + 3 * 64] = y3;
            yb[sb + 4 * 64] = y4;
        }
        __syncthreads();
        // ---------------- residual + LN2 (reduce the 2 j-halves) ----------------
        if (act) {
            int R = ai * NS + at;            // block row 0..319
            int igR = R / 80, rm = R % 80;
            int mtR = rm / 16, cR = rm & 15;
            float yr[ND];
#pragma unroll
            for (int d = 0; d < ND; ++d) {
                int gR = d >> 2, iR = d & 3;
                int o0 = (((0 * 4 + igR) * 5 + mtR) * 64 + gR * 16 + cR) * 4 + iR;
                int o1 = (((1 * 4 + igR) * 5 + mtR) * 64 + gR * 16 + cR) * 4 + iR;
                yr[d] = xs[R * ND + d] + ybuf[o0] + ybuf[o1] + b2[l * ND + d];
            }
            float m = 0.f;
#pragma unroll
            for (int d = 0; d < ND; ++d) m += yr[d];
            m *= (1.f / ND);
            float va = 0.f;
#pragma unroll
            for (int d = 0; d < ND; ++d) { float dv = yr[d] - m; va += dv * dv; }
            va *= (1.f / ND);
            float r = rsqrtf(va + EPSV);
#pragma unroll
            for (int d = 0; d < ND; ++d)
                xs[R * ND + d] = (yr[d] - m) * r * g2[l * ND + d] + be2[l * ND + d];
        }
        __syncthreads();
    }
    // ---------------- classification head + softmax ----------------
    if (tid < ITEMS) {
        float l0 = bfc[0], l1 = bfc[1];
#pragma unroll
        for (int v = 0; v < ROW; ++v) {
            float xv = xs[tid * ROW + v];
            l0 += Wfc[v] * xv;
            l1 += Wfc[ROW + v] * xv;
        }
        float mx = fmaxf(l0, l1);
        float e0 = __expf(l0 - mx), e1 = __expf(l1 - mx);
        float inv = 1.f / (e0 + e1);
        out[(size_t)(base + tid) * 2 + 0] = e0 * inv;
        out[(size_t)(base + tid) * 2 + 1] = e1 * inv;
    }
}

extern "C" void kernel_launch(void* const* d_in, const int* in_sizes, int n_in,
                              void* d_out, int out_size, void* d_ws, size_t ws_size,
                              hipStream_t stream) {
    (void)in_sizes; (void)n_in; (void)d_ws; (void)ws_size; (void)out_size;
    const float* x = (const float*)d_in[0];
    const float* Wq = (const float*)d_in[1];
    const float* bq = (const float*)d_in[2];
    const float* Wk = (const float*)d_in[3];
    const float* bk = (const float*)d_in[4];
    const float* Wv = (const float*)d_in[5];
    const float* bv = (const float*)d_in[6];
    const float* Wo = (const float*)d_in[7];
    const float* bo = (const float*)d_in[8];
    const float* W1 = (const float*)d_in[9];
    const float* b1 = (const float*)d_in[10];
    const float* W2 = (const float*)d_in[11];
    const float* b2 = (const float*)d_in[12];
    const float* g1 = (const float*)d_in[13];
    const float* be1 = (const float*)d_in[14];
    const float* g2 = (const float*)d_in[15];
    const float* be2 = (const float*)d_in[16];
    const float* Wfc = (const float*)d_in[17];
    const float* bfc = (const float*)d_in[18];
    float* out = (float*)d_out;

    const int npack = 2 * NL * NJT * 64 + NL * NJT * 4;  // 67584
    hipLaunchKernelGGL(pack_kernel, dim3((npack + 255) / 256), dim3(256), 0, stream,
                       W1, b1, W2);
    hipLaunchKernelGGL(encoder_kernel, dim3(NBATCH / ITEMS), dim3(TPB), 0, stream,
                       x, Wq, bq, Wk, bk, Wv, bv, Wo, bo, b2, g1, be1, g2, be2,
                       Wfc, bfc, out);
}

// Round 5
// 94.133 us; speedup vs baseline: 4.2810x; 1.0581x over previous
//
#include <hip/hip_runtime.h>
#include <math.h>

#define NL 4
#define NBATCH 16384
#define NS 5
#define ND 6
#define NH 2
#define NHD 3
#define NFF 2048
#define EPSV 1e-5f

#define ITEMS 32               // items per block -> grid 512 -> 2 blocks/CU
#define TPB 512                // 8 waves
#define NJT 128                // j-tiles of 16 per layer
#define ROW (NS * ND)          // 30
#define NVAL (ITEMS * ROW)     // 960

typedef __fp16 v4h __attribute__((ext_vector_type(4)));
typedef __fp16 v2h __attribute__((ext_vector_type(2)));
typedef float f32x4 __attribute__((ext_vector_type(4)));

union HU { uint2 u; v4h h; __fp16 f[4]; };

__device__ inline unsigned pk_u32(float a, float b) {
    union { v2h h; unsigned u; } x;
    x.h = __builtin_amdgcn_cvt_pkrtz(a, b);
    return x.u;
}

// Prepacked MFMA A-fragments (f16) + b1 C-fragments (f32).
// A-frag layout for v_mfma_f32_16x16x16f16: lane l holds A[row=l&15][k=4*(l>>4)+e]
__device__ __align__(8) uint2 W1T[NL * NJT * 64];    // GEMM1 A: W1[j=row][k=d(pad16)]
__device__ __align__(8) uint2 W2T[NL * NJT * 64];    // GEMM2 A: W2[d=row(pad16)][k=j]
__device__ __align__(16) f32x4 B1T[NL * NJT * 4];    // b1 per (jt, lanegroup)

__global__ void pack_kernel(const float* __restrict__ W1,
                            const float* __restrict__ b1,
                            const float* __restrict__ W2) {
    int idx = blockIdx.x * 256 + threadIdx.x;
    if (idx < NL * NJT * 64) {              // W1T
        int lane = idx & 63, jt = (idx >> 6) & 127, l = idx >> 13;
        int cc = lane & 15, g = lane >> 4;
        HU o; o.u = make_uint2(0u, 0u);
        if (g < 2) {
            int j = jt * 16 + cc;
#pragma unroll
            for (int e = 0; e < 4; ++e) {
                int k = 4 * g + e;
                o.f[e] = (k < ND) ? (__fp16)W1[(size_t)(l * NFF + j) * ND + k]
                                  : (__fp16)0.f;
            }
        }
        W1T[idx] = o.u;
    } else if (idx < 2 * NL * NJT * 64) {   // W2T
        int t = idx - NL * NJT * 64;
        int lane = t & 63, jt = (t >> 6) & 127, l = t >> 13;
        int d = lane & 15, g = lane >> 4;
        HU o; o.u = make_uint2(0u, 0u);
        if (d < ND) {
#pragma unroll
            for (int e = 0; e < 4; ++e) {
                int j = jt * 16 + 4 * g + e;
                o.f[e] = (__fp16)W2[(size_t)(l * ND + d) * NFF + j];
            }
        }
        W2T[t] = o.u;
    } else if (idx < 2 * NL * NJT * 64 + NL * NJT * 4) {  // B1T
        int t = idx - 2 * NL * NJT * 64;    // ((l*128+jt)*4+g)
        int g = t & 3, jt = (t >> 2) & 127, l = t >> 9;
        f32x4 v;
        v.x = b1[l * NFF + jt * 16 + 4 * g + 0];
        v.y = b1[l * NFF + jt * 16 + 4 * g + 1];
        v.z = b1[l * NFF + jt * 16 + 4 * g + 2];
        v.w = b1[l * NFF + jt * 16 + 4 * g + 3];
        B1T[t] = v;
    }
}

__global__ __launch_bounds__(TPB, 4) void encoder_kernel(
    const float* __restrict__ xin,
    const float* __restrict__ Wq, const float* __restrict__ bq,
    const float* __restrict__ Wk, const float* __restrict__ bk,
    const float* __restrict__ Wv, const float* __restrict__ bv,
    const float* __restrict__ Wo, const float* __restrict__ bo,
    const float* __restrict__ b2,
    const float* __restrict__ g1, const float* __restrict__ be1,
    const float* __restrict__ g2, const float* __restrict__ be2,
    const float* __restrict__ Wfc, const float* __restrict__ bfc,
    float* __restrict__ out) {
    __shared__ float xs[NVAL];                   // 3.84 KB x state
    __shared__ float kvs[ITEMS * NS * 2 * ND];   // 7.68 KB k,v
    __shared__ float ybuf[4 * 2 * 5 * 64 * 4];   // 40.96 KB y frags (jq, ig, mt, lane, 4)

    const int tid = threadIdx.x;
    const int base = blockIdx.x * ITEMS;

    if (tid < NVAL / 4)
        ((float4*)xs)[tid] = ((const float4*)(xin + (size_t)base * ROW))[tid];
    __syncthreads();

    const bool act = tid < ITEMS * NS;  // 160 attention threads: (item, token)
    const int ai = tid / NS;
    const int at = tid - ai * NS;

    // FFN wave roles: wave w: item-group ig (16 items = 5 M-tiles), j-quarter jq
    const int lane = tid & 63;
    const int w = tid >> 6;
    const int jq = w & 3, ig = w >> 2;
    const int c16 = lane & 15, g = lane >> 4;

    for (int l = 0; l < NL; ++l) {
        // ---------------- attention: qkv ----------------
        float xr[ND], qv[ND];
        if (act) {
#pragma unroll
            for (int d = 0; d < ND; ++d) xr[d] = xs[(ai * NS + at) * ND + d];
#pragma unroll
            for (int d = 0; d < ND; ++d) {
                float aq = bq[l * ND + d], ak = bk[l * ND + d], av = bv[l * ND + d];
#pragma unroll
                for (int e = 0; e < ND; ++e) {
                    aq += Wq[(l * ND + d) * ND + e] * xr[e];
                    ak += Wk[(l * ND + d) * ND + e] * xr[e];
                    av += Wv[(l * ND + d) * ND + e] * xr[e];
                }
                qv[d] = aq;
                kvs[(ai * NS + at) * 2 * ND + d] = ak;
                kvs[(ai * NS + at) * 2 * ND + ND + d] = av;
            }
        }
        __syncthreads();
        // ---------------- attention: scores/ctx/outproj/LN1 ----------------
        if (act) {
            const float scale = 0.57735026919f;  // 1/sqrt(HD)
            float ctx[ND];
#pragma unroll
            for (int h = 0; h < NH; ++h) {
                float sc[NS];
                float mx = -1e30f;
#pragma unroll
                for (int u = 0; u < NS; ++u) {
                    float s = 0.f;
#pragma unroll
                    for (int d = 0; d < NHD; ++d)
                        s += qv[h * NHD + d] * kvs[(ai * NS + u) * 2 * ND + h * NHD + d];
                    s *= scale;
                    sc[u] = s;
                    mx = fmaxf(mx, s);
                }
                float sum = 0.f;
#pragma unroll
                for (int u = 0; u < NS; ++u) {
                    sc[u] = __expf(sc[u] - mx);
                    sum += sc[u];
                }
                float inv = 1.f / sum;
#pragma unroll
                for (int d = 0; d < NHD; ++d) {
                    float cx = 0.f;
#pragma unroll
                    for (int u = 0; u < NS; ++u)
                        cx += sc[u] * kvs[(ai * NS + u) * 2 * ND + ND + h * NHD + d];
                    ctx[h * NHD + d] = cx * inv;
                }
            }
            float yr[ND];
#pragma unroll
            for (int d = 0; d < ND; ++d) {
                float a = bo[l * ND + d];
#pragma unroll
                for (int e = 0; e < ND; ++e) a += Wo[(l * ND + d) * ND + e] * ctx[e];
                yr[d] = a + xr[d];
            }
            float m = 0.f;
#pragma unroll
            for (int d = 0; d < ND; ++d) m += yr[d];
            m *= (1.f / ND);
            float va = 0.f;
#pragma unroll
            for (int d = 0; d < ND; ++d) { float dv = yr[d] - m; va += dv * dv; }
            va *= (1.f / ND);
            float r = rsqrtf(va + EPSV);
#pragma unroll
            for (int d = 0; d < ND; ++d)
                xs[(ai * NS + at) * ND + d] =
                    (yr[d] - m) * r * g1[l * ND + d] + be1[l * ND + d];
        }
        __syncthreads();
        // ---------------- FFN: MFMA, all 8 waves ----------------
        // X B-frags per M-tile: lane holds X^T[k=4g+e][m=c16] (k=d pad 6->16)
        v4h xb[5];
#pragma unroll
        for (int mt = 0; mt < 5; ++mt) {
            HU u; u.u = make_uint2(0u, 0u);
            int row = ig * 80 + mt * 16 + c16;
            if (g == 0) {
                float2 a = *(const float2*)&xs[row * 6];
                float2 b = *(const float2*)&xs[row * 6 + 2];
                u.u.x = pk_u32(a.x, a.y);
                u.u.y = pk_u32(b.x, b.y);
            } else if (g == 1) {
                float2 a = *(const float2*)&xs[row * 6 + 4];
                u.u.x = pk_u32(a.x, a.y);
            }
            xb[mt] = u.h;
        }
        f32x4 y0 = {0.f, 0.f, 0.f, 0.f}, y1 = y0, y2 = y0, y3 = y0, y4 = y0;
        const uint2* w1p = W1T + ((size_t)(l * NJT + jq * 32)) * 64 + lane;
        const uint2* w2p = W2T + ((size_t)(l * NJT + jq * 32)) * 64 + lane;
        const f32x4* b1p = B1T + ((size_t)(l * NJT + jq * 32)) * 4 + g;
#pragma unroll 2
        for (int jt = 0; jt < 32; ++jt) {
            HU a1; a1.u = w1p[jt * 64];
            HU a2; a2.u = w2p[jt * 64];
            f32x4 bb = b1p[jt * 4];
#define FFN_STEP(YREG, XB)                                                      \
            {                                                                   \
                f32x4 hh = __builtin_amdgcn_mfma_f32_16x16x16f16(               \
                    a1.h, (XB), bb, 0, 0, 0);                                   \
                HU hb;                                                          \
                hb.u.x = pk_u32(fmaxf(hh.x, 0.f), fmaxf(hh.y, 0.f));            \
                hb.u.y = pk_u32(fmaxf(hh.z, 0.f), fmaxf(hh.w, 0.f));            \
                YREG = __builtin_amdgcn_mfma_f32_16x16x16f16(                   \
                    a2.h, hb.h, YREG, 0, 0, 0);                                 \
            }
            FFN_STEP(y0, xb[0])
            FFN_STEP(y1, xb[1])
            FFN_STEP(y2, xb[2])
            FFN_STEP(y3, xb[3])
            FFN_STEP(y4, xb[4])
#undef FFN_STEP
        }
        // write y fragments: ybuf[jq][ig][mt][lane][0..3]
        {
            f32x4* yb = (f32x4*)ybuf;
            int sb = ((jq * 2 + ig) * 5) * 64 + lane;
            yb[sb + 0 * 64] = y0;
            yb[sb + 1 * 64] = y1;
            yb[sb + 2 * 64] = y2;
            yb[sb + 3 * 64] = y3;
            yb[sb + 4 * 64] = y4;
        }
        __syncthreads();
        // ---------------- residual + LN2 (reduce the 4 j-quarters) ----------------
        if (act) {
            int R = ai * NS + at;            // block row 0..159
            int igR = R / 80, rm = R % 80;
            int mtR = rm / 16, cR = rm & 15;
            float yr[ND];
#pragma unroll
            for (int d = 0; d < ND; ++d) {
                int gR = d >> 2, iR = d & 3;
                float s = 0.f;
#pragma unroll
                for (int q = 0; q < 4; ++q)
                    s += ybuf[(((q * 2 + igR) * 5 + mtR) * 64 + gR * 16 + cR) * 4 + iR];
                yr[d] = xs[R * ND + d] + s + b2[l * ND + d];
            }
            float m = 0.f;
#pragma unroll
            for (int d = 0; d < ND; ++d) m += yr[d];
            m *= (1.f / ND);
            float va = 0.f;
#pragma unroll
            for (int d = 0; d < ND; ++d) { float dv = yr[d] - m; va += dv * dv; }
            va *= (1.f / ND);
            float r = rsqrtf(va + EPSV);
#pragma unroll
            for (int d = 0; d < ND; ++d)
                xs[R * ND + d] = (yr[d] - m) * r * g2[l * ND + d] + be2[l * ND + d];
        }
        __syncthreads();
    }
    // ---------------- classification head + softmax ----------------
    if (tid < ITEMS) {
        float l0 = bfc[0], l1 = bfc[1];
#pragma unroll
        for (int v = 0; v < ROW; ++v) {
            float xv = xs[tid * ROW + v];
            l0 += Wfc[v] * xv;
            l1 += Wfc[ROW + v] * xv;
        }
        float mx = fmaxf(l0, l1);
        float e0 = __expf(l0 - mx), e1 = __expf(l1 - mx);
        float inv = 1.f / (e0 + e1);
        out[(size_t)(base + tid) * 2 + 0] = e0 * inv;
        out[(size_t)(base + tid) * 2 + 1] = e1 * inv;
    }
}

extern "C" void kernel_launch(void* const* d_in, const int* in_sizes, int n_in,
                              void* d_out, int out_size, void* d_ws, size_t ws_size,
                              hipStream_t stream) {
    (void)in_sizes; (void)n_in; (void)d_ws; (void)ws_size; (void)out_size;
    const float* x = (const float*)d_in[0];
    const float* Wq = (const float*)d_in[1];
    const float* bq = (const float*)d_in[2];
    const float* Wk = (const float*)d_in[3];
    const float* bk = (const float*)d_in[4];
    const float* Wv = (const float*)d_in[5];
    const float* bv = (const float*)d_in[6];
    const float* Wo = (const float*)d_in[7];
    const float* bo = (const float*)d_in[8];
    const float* W1 = (const float*)d_in[9];
    const float* b1 = (const float*)d_in[10];
    const float* W2 = (const float*)d_in[11];
    const float* b2 = (const float*)d_in[12];
    const float* g1 = (const float*)d_in[13];
    const float* be1 = (const float*)d_in[14];
    const float* g2 = (const float*)d_in[15];
    const float* be2 = (const float*)d_in[16];
    const float* Wfc = (const float*)d_in[17];
    const float* bfc = (const float*)d_in[18];
    float* out = (float*)d_out;

    const int npack = 2 * NL * NJT * 64 + NL * NJT * 4;  // 67584
    hipLaunchKernelGGL(pack_kernel, dim3((npack + 255) / 256), dim3(256), 0, stream,
                       W1, b1, W2);
    hipLaunchKernelGGL(encoder_kernel, dim3(NBATCH / ITEMS), dim3(TPB), 0, stream,
                       x, Wq, bq, Wk, bk, Wv, bv, Wo, bo, b2, g1, be1, g2, be2,
                       Wfc, bfc, out);
}

// Round 7
// 69.632 us; speedup vs baseline: 5.7873x; 1.3519x over previous
//
#include <hip/hip_runtime.h>
#include <math.h>

#define NL 4
#define NBATCH 16384
#define NS 5
#define ND 6
#define NH 2
#define NHD 3
#define NFF 2048
#define EPSV 1e-5f

#define ITEMS 32               // items per block -> grid 512 -> 2 blocks/CU
#define TPB 512                // 8 waves
#define NJT 128                // j-tiles of 16 per layer
#define ROW (NS * ND)          // 30
#define NVAL (ITEMS * ROW)     // 960

typedef __fp16 v4h __attribute__((ext_vector_type(4)));
typedef __fp16 v2h __attribute__((ext_vector_type(2)));
typedef float f32x4 __attribute__((ext_vector_type(4)));

union HU { uint2 u; v4h h; __fp16 f[4]; };

__device__ inline unsigned pk_u32(float a, float b) {
    union { v2h h; unsigned u; } x;
    x.h = __builtin_amdgcn_cvt_pkrtz(a, b);
    return x.u;
}

// Combined prepacked MFMA A-fragments (f16): per (l, jt, lane) one uint4 =
// {W1frag(8B), W2frag(8B)}. A-frag layout for v_mfma_f32_16x16x16f16:
// lane l holds A[row=l&15][k=4*(l>>4)+e]
__device__ __align__(16) uint4 WPK[NL * NJT * 64];
__device__ __align__(16) f32x4 B1T[NL * NJT * 4];    // b1 per (jt, lanegroup)

__global__ void pack_kernel(const float* __restrict__ W1,
                            const float* __restrict__ b1,
                            const float* __restrict__ W2) {
    int idx = blockIdx.x * 256 + threadIdx.x;
    if (idx < NL * NJT * 64) {              // WPK
        int lane = idx & 63, jt = (idx >> 6) & 127, l = idx >> 13;
        int cc = lane & 15, g = lane >> 4;
        HU o1; o1.u = make_uint2(0u, 0u);
        if (g < 2) {
            int j = jt * 16 + cc;
#pragma unroll
            for (int e = 0; e < 4; ++e) {
                int k = 4 * g + e;
                o1.f[e] = (k < ND) ? (__fp16)W1[(size_t)(l * NFF + j) * ND + k]
                                   : (__fp16)0.f;
            }
        }
        HU o2; o2.u = make_uint2(0u, 0u);
        if (cc < ND) {
#pragma unroll
            for (int e = 0; e < 4; ++e) {
                int j = jt * 16 + 4 * g + e;
                o2.f[e] = (__fp16)W2[(size_t)(l * ND + cc) * NFF + j];
            }
        }
        WPK[idx] = make_uint4(o1.u.x, o1.u.y, o2.u.x, o2.u.y);
    } else if (idx < NL * NJT * 64 + NL * NJT * 4) {  // B1T
        int t = idx - NL * NJT * 64;    // ((l*128+jt)*4+g)
        int g = t & 3, jt = (t >> 2) & 127, l = t >> 9;
        f32x4 v;
        v.x = b1[l * NFF + jt * 16 + 4 * g + 0];
        v.y = b1[l * NFF + jt * 16 + 4 * g + 1];
        v.z = b1[l * NFF + jt * 16 + 4 * g + 2];
        v.w = b1[l * NFF + jt * 16 + 4 * g + 3];
        B1T[t] = v;
    }
}

__global__ __launch_bounds__(TPB, 4) void encoder_kernel(
    const float* __restrict__ xin,
    const float* __restrict__ Wq, const float* __restrict__ bq,
    const float* __restrict__ Wk, const float* __restrict__ bk,
    const float* __restrict__ Wv, const float* __restrict__ bv,
    const float* __restrict__ Wo, const float* __restrict__ bo,
    const float* __restrict__ b2,
    const float* __restrict__ g1, const float* __restrict__ be1,
    const float* __restrict__ g2, const float* __restrict__ be2,
    const float* __restrict__ Wfc, const float* __restrict__ bfc,
    float* __restrict__ out) {
    __shared__ float xs[NVAL];                   // 3.84 KB x state
    __shared__ float kvs[ITEMS * NS * 2 * ND];   // 7.68 KB k,v
    __shared__ float ybuf[4 * 2 * 5 * 64 * 4];   // 40.96 KB y frags (jq, ig, mt, lane, 4)

    const int tid = threadIdx.x;
    const int base = blockIdx.x * ITEMS;

    if (tid < NVAL / 4)
        ((float4*)xs)[tid] = ((const float4*)(xin + (size_t)base * ROW))[tid];
    __syncthreads();

    const bool act = tid < ITEMS * NS;  // 160 attention threads: (item, token)
    const int ai = tid / NS;
    const int at = tid - ai * NS;

    // FFN wave roles: wave w: item-group ig (16 items = 5 M-tiles), j-quarter jq
    const int lane = tid & 63;
    const int w = tid >> 6;
    const int jq = w & 3, ig = w >> 2;
    const int c16 = lane & 15, g = lane >> 4;

    v4h hz; hz.x = hz.y = hz.z = hz.w = (__fp16)0.f;

    for (int l = 0; l < NL; ++l) {
        // ---- issue first FFN weight prefetch group (independent of xs) ----
        const uint4* wp = WPK + (size_t)(l * NJT + jq * 32) * 64 + lane;
        const f32x4* b1p = B1T + (size_t)(l * NJT + jq * 32) * 4 + g;
        uint4 wpf[2][4]; f32x4 bpf[2][4];
#pragma unroll
        for (int p = 0; p < 4; ++p) { wpf[0][p] = wp[p * 64]; bpf[0][p] = b1p[p * 4]; }

        // ---------------- attention: qkv ----------------
        float xr[ND], qv[ND];
        if (act) {
#pragma unroll
            for (int d = 0; d < ND; ++d) xr[d] = xs[(ai * NS + at) * ND + d];
#pragma unroll
            for (int d = 0; d < ND; ++d) {
                float aq = bq[l * ND + d], ak = bk[l * ND + d], av = bv[l * ND + d];
#pragma unroll
                for (int e = 0; e < ND; ++e) {
                    aq += Wq[(l * ND + d) * ND + e] * xr[e];
                    ak += Wk[(l * ND + d) * ND + e] * xr[e];
                    av += Wv[(l * ND + d) * ND + e] * xr[e];
                }
                qv[d] = aq;
                kvs[(ai * NS + at) * 2 * ND + d] = ak;
                kvs[(ai * NS + at) * 2 * ND + ND + d] = av;
            }
        }
        __syncthreads();
        // ---------------- attention: scores/ctx/outproj/LN1 ----------------
        if (act) {
            const float scale = 0.57735026919f;  // 1/sqrt(HD)
            float ctx[ND];
#pragma unroll
            for (int h = 0; h < NH; ++h) {
                float sc[NS];
                float mx = -1e30f;
#pragma unroll
                for (int u = 0; u < NS; ++u) {
                    float s = 0.f;
#pragma unroll
                    for (int d = 0; d < NHD; ++d)
                        s += qv[h * NHD + d] * kvs[(ai * NS + u) * 2 * ND + h * NHD + d];
                    s *= scale;
                    sc[u] = s;
                    mx = fmaxf(mx, s);
                }
                float sum = 0.f;
#pragma unroll
                for (int u = 0; u < NS; ++u) {
                    sc[u] = __expf(sc[u] - mx);
                    sum += sc[u];
                }
                float inv = 1.f / sum;
#pragma unroll
                for (int d = 0; d < NHD; ++d) {
                    float cx = 0.f;
#pragma unroll
                    for (int u = 0; u < NS; ++u)
                        cx += sc[u] * kvs[(ai * NS + u) * 2 * ND + ND + h * NHD + d];
                    ctx[h * NHD + d] = cx * inv;
                }
            }
            float yr[ND];
#pragma unroll
            for (int d = 0; d < ND; ++d) {
                float a = bo[l * ND + d];
#pragma unroll
                for (int e = 0; e < ND; ++e) a += Wo[(l * ND + d) * ND + e] * ctx[e];
                yr[d] = a + xr[d];
            }
            float m = 0.f;
#pragma unroll
            for (int d = 0; d < ND; ++d) m += yr[d];
            m *= (1.f / ND);
            float va = 0.f;
#pragma unroll
            for (int d = 0; d < ND; ++d) { float dv = yr[d] - m; va += dv * dv; }
            va *= (1.f / ND);
            float r = rsqrtf(va + EPSV);
#pragma unroll
            for (int d = 0; d < ND; ++d)
                xs[(ai * NS + at) * ND + d] =
                    (yr[d] - m) * r * g1[l * ND + d] + be1[l * ND + d];
        }
        __syncthreads();
        // ---------------- FFN: MFMA, all 8 waves, pipelined weight stream ----
        // X B-frags per M-tile: lane holds X^T[k=4g+e][m=c16] (k=d pad 6->16)
        v4h xb[5];
#pragma unroll
        for (int mt = 0; mt < 5; ++mt) {
            HU u; u.u = make_uint2(0u, 0u);
            int row = ig * 80 + mt * 16 + c16;
            if (g == 0) {
                float2 a = *(const float2*)&xs[row * 6];
                float2 b = *(const float2*)&xs[row * 6 + 2];
                u.u.x = pk_u32(a.x, a.y);
                u.u.y = pk_u32(b.x, b.y);
            } else if (g == 1) {
                float2 a = *(const float2*)&xs[row * 6 + 4];
                u.u.x = pk_u32(a.x, a.y);
            }
            xb[mt] = u.h;
        }
        f32x4 y0 = {0.f, 0.f, 0.f, 0.f}, y1 = y0, y2 = y0, y3 = y0, y4 = y0;
#pragma unroll
        for (int gq = 0; gq < 8; ++gq) {
            const int cur = gq & 1, nxt = cur ^ 1;
            if (gq < 7) {
#pragma unroll
                for (int p = 0; p < 4; ++p) {
                    wpf[nxt][p] = wp[(gq * 4 + 4 + p) * 64];
                    bpf[nxt][p] = b1p[(gq * 4 + 4 + p) * 4];
                }
            }
#pragma unroll
            for (int p = 0; p < 4; ++p) {
                HU a1; a1.u = make_uint2(wpf[cur][p].x, wpf[cur][p].y);
                HU a2; a2.u = make_uint2(wpf[cur][p].z, wpf[cur][p].w);
                f32x4 bb = bpf[cur][p];
#define FFN_STEP(YREG, XB)                                                      \
                {                                                               \
                    f32x4 hh = __builtin_amdgcn_mfma_f32_16x16x16f16(           \
                        a1.h, (XB), bb, 0, 0, 0);                               \
                    HU hb;                                                      \
                    hb.u.x = pk_u32(hh.x, hh.y);                                \
                    hb.u.y = pk_u32(hh.z, hh.w);                                \
                    hb.h = __builtin_elementwise_max(hb.h, hz);                 \
                    YREG = __builtin_amdgcn_mfma_f32_16x16x16f16(               \
                        a2.h, hb.h, YREG, 0, 0, 0);                             \
                }
                FFN_STEP(y0, xb[0])
                FFN_STEP(y1, xb[1])
                FFN_STEP(y2, xb[2])
                FFN_STEP(y3, xb[3])
                FFN_STEP(y4, xb[4])
#undef FFN_STEP
            }
        }
        // write y fragments: ybuf[jq][ig][mt][lane][0..3]
        {
            f32x4* yb = (f32x4*)ybuf;
            int sb = ((jq * 2 + ig) * 5) * 64 + lane;
            yb[sb + 0 * 64] = y0;
            yb[sb + 1 * 64] = y1;
            yb[sb + 2 * 64] = y2;
            yb[sb + 3 * 64] = y3;
            yb[sb + 4 * 64] = y4;
        }
        __syncthreads();
        // ---------------- residual + LN2 (reduce the 4 j-quarters) ----------------
        if (act) {
            int R = ai * NS + at;            // block row 0..159
            int igR = R / 80, rm = R % 80;
            int mtR = rm / 16, cR = rm & 15;
            float yr[ND];
#pragma unroll
            for (int d = 0; d < ND; ++d) {
                int gR = d >> 2, iR = d & 3;
                float s = 0.f;
#pragma unroll
                for (int q = 0; q < 4; ++q)
                    s += ybuf[(((q * 2 + igR) * 5 + mtR) * 64 + gR * 16 + cR) * 4 + iR];
                yr[d] = xs[R * ND + d] + s + b2[l * ND + d];
            }
            float m = 0.f;
#pragma unroll
            for (int d = 0; d < ND; ++d) m += yr[d];
            m *= (1.f / ND);
            float va = 0.f;
#pragma unroll
            for (int d = 0; d < ND; ++d) { float dv = yr[d] - m; va += dv * dv; }
            va *= (1.f / ND);
            float r = rsqrtf(va + EPSV);
#pragma unroll
            for (int d = 0; d < ND; ++d)
                xs[R * ND + d] = (yr[d] - m) * r * g2[l * ND + d] + be2[l * ND + d];
        }
        __syncthreads();
    }
    // ---------------- classification head + softmax ----------------
    if (tid < ITEMS) {
        float l0 = bfc[0], l1 = bfc[1];
#pragma unroll
        for (int v = 0; v < ROW; ++v) {
            float xv = xs[tid * ROW + v];
            l0 += Wfc[v] * xv;
            l1 += Wfc[ROW + v] * xv;
        }
        float mx = fmaxf(l0, l1);
        float e0 = __expf(l0 - mx), e1 = __expf(l1 - mx);
        float inv = 1.f / (e0 + e1);
        out[(size_t)(base + tid) * 2 + 0] = e0 * inv;
        out[(size_t)(base + tid) * 2 + 1] = e1 * inv;
    }
}

extern "C" void kernel_launch(void* const* d_in, const int* in_sizes, int n_in,
                              void* d_out, int out_size, void* d_ws, size_t ws_size,
                              hipStream_t stream) {
    (void)in_sizes; (void)n_in; (void)d_ws; (void)ws_size; (void)out_size;
    const float* x = (const float*)d_in[0];
    const float* Wq = (const float*)d_in[1];
    const float* bq = (const float*)d_in[2];
    const float* Wk = (const float*)d_in[3];
    const float* bk = (const float*)d_in[4];
    const float* Wv = (const float*)d_in[5];
    const float* bv = (const float*)d_in[6];
    const float* Wo = (const float*)d_in[7];
    const float* bo = (const float*)d_in[8];
    const float* W1 = (const float*)d_in[9];
    const float* b1 = (const float*)d_in[10];
    const float* W2 = (const float*)d_in[11];
    const float* b2 = (const float*)d_in[12];
    const float* g1 = (const float*)d_in[13];
    const float* be1 = (const float*)d_in[14];
    const float* g2 = (const float*)d_in[15];
    const float* be2 = (const float*)d_in[16];
    const float* Wfc = (const float*)d_in[17];
    const float* bfc = (const float*)d_in[18];
    float* out = (float*)d_out;

    const int npack = NL * NJT * 64 + NL * NJT * 4;  // 34816
    hipLaunchKernelGGL(pack_kernel, dim3((npack + 255) / 256), dim3(256), 0, stream,
                       W1, b1, W2);
    hipLaunchKernelGGL(encoder_kernel, dim3(NBATCH / ITEMS), dim3(TPB), 0, stream,
                       x, Wq, bq, Wk, bk, Wv, bv, Wo, bo, b2, g1, be1, g2, be2,
                       Wfc, bfc, out);
}

// Round 8
// 61.678 us; speedup vs baseline: 6.5336x; 1.1290x over previous
//
#include <hip/hip_runtime.h>
#include <math.h>

#define NL 4
#define NBATCH 16384
#define NS 5
#define ND 6
#define NH 2
#define NHD 3
#define NFF 2048
#define EPSV 1e-5f

#define ITEMS 32               // items per block -> grid 512 -> 2 blocks/CU
#define TPB 512                // 8 waves
#define NPAIR 64               // jt-pairs (32 j's) per layer
#define ROW (NS * ND)          // 30
#define NVAL (ITEMS * ROW)     // 960

typedef __fp16 v8h __attribute__((ext_vector_type(8)));
typedef __fp16 v2h __attribute__((ext_vector_type(2)));
typedef float f32x4 __attribute__((ext_vector_type(4)));

union HU8 { uint4 u; v8h h; __fp16 f[8]; };

__device__ inline unsigned pk_u32(float a, float b) {
    union { v2h h; unsigned u; } x;
    x.h = __builtin_amdgcn_cvt_pkrtz(a, b);
    return x.u;
}
__device__ inline unsigned packh(float a, float b) {
    union { __fp16 h[2]; unsigned u; } x;
    x.h[0] = (__fp16)a; x.h[1] = (__fp16)b; return x.u;
}

// Prepacked A-fragments for v_mfma_f32_16x16x32_f16 (lane l: row=l&15,
// k-slot (g=l>>4, e=0..7); A and B use the same (g,e)->k map so the true
// internal k order cancels).
// W1A/W1B: per (l, pair): W1 row j=jt*16+(l&15), elems e<6 = W1[j][e],
//          e==6 = b1[j] (bias via constant-1 in x-frag), only g==0 nonzero.
// W2P: per (l, pair): W2[d=l&15][j(g,e)], j(g,e)= p*32 + (e<4 ? 4g+e : 16+4g+e-4)
__device__ __align__(16) uint4 W1A[NL * NPAIR * 64];
__device__ __align__(16) uint4 W1B[NL * NPAIR * 64];
__device__ __align__(16) uint4 W2P[NL * NPAIR * 64];

__global__ void pack_kernel(const float* __restrict__ W1,
                            const float* __restrict__ b1,
                            const float* __restrict__ W2) {
    const int TOT = NL * NPAIR * 64;  // 16384
    int idx = blockIdx.x * 256 + threadIdx.x;
    if (idx >= 3 * TOT) return;
    int arr = idx / TOT, t = idx - arr * TOT;
    int lane = t & 63, p = (t >> 6) & 63, l = t >> 12;
    int r = lane & 15, g = lane >> 4;
    HU8 o; o.u = make_uint4(0u, 0u, 0u, 0u);
    if (arr < 2) {                      // W1A (jt=2p) / W1B (jt=2p+1)
        if (g == 0) {
            int j = (2 * p + arr) * 16 + r;
#pragma unroll
            for (int e = 0; e < ND; ++e)
                o.f[e] = (__fp16)W1[(size_t)(l * NFF + j) * ND + e];
            o.f[6] = (__fp16)b1[l * NFF + j];
            o.f[7] = (__fp16)0.f;
        }
        if (arr == 0) W1A[t] = o.u; else W1B[t] = o.u;
    } else {                            // W2P
        if (r < ND) {
#pragma unroll
            for (int e = 0; e < 8; ++e) {
                int j = p * 32 + ((e < 4) ? (4 * g + e) : (16 + 4 * g + e - 4));
                o.f[e] = (__fp16)W2[(size_t)(l * ND + r) * NFF + j];
            }
        }
        W2P[t] = o.u;
    }
}

__global__ __launch_bounds__(TPB, 4) void encoder_kernel(
    const float* __restrict__ xin,
    const float* __restrict__ Wq, const float* __restrict__ bq,
    const float* __restrict__ Wk, const float* __restrict__ bk,
    const float* __restrict__ Wv, const float* __restrict__ bv,
    const float* __restrict__ Wo, const float* __restrict__ bo,
    const float* __restrict__ b2,
    const float* __restrict__ g1, const float* __restrict__ be1,
    const float* __restrict__ g2, const float* __restrict__ be2,
    const float* __restrict__ Wfc, const float* __restrict__ bfc,
    float* __restrict__ out) {
    __shared__ float xs[NVAL];                   // 3.84 KB x state
    __shared__ float kvs[ITEMS * NS * 2 * ND];   // 7.68 KB k,v
    __shared__ float ybuf[4 * 2 * 5 * 64 * 4];   // 40.96 KB y frags (jq, ig, mt, lane, 4)

    const int tid = threadIdx.x;
    const int base = blockIdx.x * ITEMS;

    if (tid < NVAL / 4)
        ((float4*)xs)[tid] = ((const float4*)(xin + (size_t)base * ROW))[tid];
    __syncthreads();

    const bool act = tid < ITEMS * NS;  // 160 attention threads: (item, token)
    const int ai = tid / NS;
    const int at = tid - ai * NS;

    // FFN wave roles: wave w: item-group ig (16 items = 5 M-tiles), j-quarter jq
    const int lane = tid & 63;
    const int w = tid >> 6;
    const int jq = w & 3, ig = w >> 2;
    const int c16 = lane & 15, g = lane >> 4;

    v8h z8; z8 = (v8h)(__fp16)0.f;
    const f32x4 cz = {0.f, 0.f, 0.f, 0.f};

    for (int l = 0; l < NL; ++l) {
        // ---- issue first FFN weight prefetch group (independent of xs) ----
        const uint4* pw1a = W1A + (size_t)(l * NPAIR + jq * 16) * 64 + lane;
        const uint4* pw1b = W1B + (size_t)(l * NPAIR + jq * 16) * 64 + lane;
        const uint4* pw2  = W2P + (size_t)(l * NPAIR + jq * 16) * 64 + lane;
        uint4 wpf[2][6];
#pragma unroll
        for (int pp = 0; pp < 2; ++pp) {
            wpf[0][pp * 3 + 0] = pw1a[pp * 64];
            wpf[0][pp * 3 + 1] = pw1b[pp * 64];
            wpf[0][pp * 3 + 2] = pw2[pp * 64];
        }

        // ---------------- attention: qkv ----------------
        float xr[ND], qv[ND];
        if (act) {
#pragma unroll
            for (int d = 0; d < ND; ++d) xr[d] = xs[(ai * NS + at) * ND + d];
#pragma unroll
            for (int d = 0; d < ND; ++d) {
                float aq = bq[l * ND + d], ak = bk[l * ND + d], av = bv[l * ND + d];
#pragma unroll
                for (int e = 0; e < ND; ++e) {
                    aq += Wq[(l * ND + d) * ND + e] * xr[e];
                    ak += Wk[(l * ND + d) * ND + e] * xr[e];
                    av += Wv[(l * ND + d) * ND + e] * xr[e];
                }
                qv[d] = aq;
                kvs[(ai * NS + at) * 2 * ND + d] = ak;
                kvs[(ai * NS + at) * 2 * ND + ND + d] = av;
            }
        }
        __syncthreads();
        // ---------------- attention: scores/ctx/outproj/LN1 ----------------
        if (act) {
            const float scale = 0.57735026919f;  // 1/sqrt(HD)
            float ctx[ND];
#pragma unroll
            for (int h = 0; h < NH; ++h) {
                float sc[NS];
                float mx = -1e30f;
#pragma unroll
                for (int u = 0; u < NS; ++u) {
                    float s = 0.f;
#pragma unroll
                    for (int d = 0; d < NHD; ++d)
                        s += qv[h * NHD + d] * kvs[(ai * NS + u) * 2 * ND + h * NHD + d];
                    s *= scale;
                    sc[u] = s;
                    mx = fmaxf(mx, s);
                }
                float sum = 0.f;
#pragma unroll
                for (int u = 0; u < NS; ++u) {
                    sc[u] = __expf(sc[u] - mx);
                    sum += sc[u];
                }
                float inv = 1.f / sum;
#pragma unroll
                for (int d = 0; d < NHD; ++d) {
                    float cx = 0.f;
#pragma unroll
                    for (int u = 0; u < NS; ++u)
                        cx += sc[u] * kvs[(ai * NS + u) * 2 * ND + ND + h * NHD + d];
                    ctx[h * NHD + d] = cx * inv;
                }
            }
            float yr[ND];
#pragma unroll
            for (int d = 0; d < ND; ++d) {
                float a = bo[l * ND + d];
#pragma unroll
                for (int e = 0; e < ND; ++e) a += Wo[(l * ND + d) * ND + e] * ctx[e];
                yr[d] = a + xr[d];
            }
            float m = 0.f;
#pragma unroll
            for (int d = 0; d < ND; ++d) m += yr[d];
            m *= (1.f / ND);
            float va = 0.f;
#pragma unroll
            for (int d = 0; d < ND; ++d) { float dv = yr[d] - m; va += dv * dv; }
            va *= (1.f / ND);
            float r = rsqrtf(va + EPSV);
#pragma unroll
            for (int d = 0; d < ND; ++d)
                xs[(ai * NS + at) * ND + d] =
                    (yr[d] - m) * r * g1[l * ND + d] + be1[l * ND + d];
        }
        __syncthreads();
        // ---------------- FFN: K=32 MFMA, all 8 waves, pipelined weights ----
        // x B-frag per M-tile: g==0 lanes hold x[d=e][m=c16] (e<6), 1.0 at e=6
        v8h xb[5];
#pragma unroll
        for (int mt = 0; mt < 5; ++mt) {
            HU8 u; u.u = make_uint4(0u, 0u, 0u, 0u);
            if (g == 0) {
                int row = ig * 80 + mt * 16 + c16;
                const float* xp = &xs[row * 6];
                u.u.x = pk_u32(xp[0], xp[1]);
                u.u.y = pk_u32(xp[2], xp[3]);
                u.u.z = pk_u32(xp[4], xp[5]);
                u.u.w = 0x00003c00u;   // f16 {1.0, 0.0} -> bias slot k=6
            }
            xb[mt] = u.h;
        }
        f32x4 y0 = cz, y1 = cz, y2 = cz, y3 = cz, y4 = cz;
#pragma unroll
        for (int gq = 0; gq < 8; ++gq) {
            const int cur = gq & 1, nxt = cur ^ 1;
            if (gq < 7) {
#pragma unroll
                for (int pp = 0; pp < 2; ++pp) {
                    int pofs = (gq * 2 + 2 + pp) * 64;
                    wpf[nxt][pp * 3 + 0] = pw1a[pofs];
                    wpf[nxt][pp * 3 + 1] = pw1b[pofs];
                    wpf[nxt][pp * 3 + 2] = pw2[pofs];
                }
            }
#pragma unroll
            for (int pp = 0; pp < 2; ++pp) {
                HU8 a1; a1.u = wpf[cur][pp * 3 + 0];
                HU8 b1f; b1f.u = wpf[cur][pp * 3 + 1];
                HU8 w2f; w2f.u = wpf[cur][pp * 3 + 2];
#define FFN_STEP(YREG, XB)                                                      \
                {                                                               \
                    f32x4 h0 = __builtin_amdgcn_mfma_f32_16x16x32_f16(          \
                        a1.h, (XB), cz, 0, 0, 0);                               \
                    f32x4 h1 = __builtin_amdgcn_mfma_f32_16x16x32_f16(          \
                        b1f.h, (XB), cz, 0, 0, 0);                              \
                    HU8 hb;                                                     \
                    hb.u.x = pk_u32(h0.x, h0.y);                                \
                    hb.u.y = pk_u32(h0.z, h0.w);                                \
                    hb.u.z = pk_u32(h1.x, h1.y);                                \
                    hb.u.w = pk_u32(h1.z, h1.w);                                \
                    hb.h = __builtin_elementwise_max(hb.h, z8);                 \
                    YREG = __builtin_amdgcn_mfma_f32_16x16x32_f16(              \
                        w2f.h, hb.h, YREG, 0, 0, 0);                            \
                }
                FFN_STEP(y0, xb[0])
                FFN_STEP(y1, xb[1])
                FFN_STEP(y2, xb[2])
                FFN_STEP(y3, xb[3])
                FFN_STEP(y4, xb[4])
#undef FFN_STEP
            }
        }
        // write y fragments: ybuf[jq][ig][mt][lane][0..3]
        {
            f32x4* yb = (f32x4*)ybuf;
            int sb = ((jq * 2 + ig) * 5) * 64 + lane;
            yb[sb + 0 * 64] = y0;
            yb[sb + 1 * 64] = y1;
            yb[sb + 2 * 64] = y2;
            yb[sb + 3 * 64] = y3;
            yb[sb + 4 * 64] = y4;
        }
        __syncthreads();
        // ---------------- residual + LN2 (reduce the 4 j-quarters) ----------------
        if (act) {
            int R = ai * NS + at;            // block row 0..159
            int igR = R / 80, rm = R % 80;
            int mtR = rm / 16, cR = rm & 15;
            float yr[ND];
#pragma unroll
            for (int d = 0; d < ND; ++d) {
                int gR = d >> 2, iR = d & 3;
                float s = 0.f;
#pragma unroll
                for (int q = 0; q < 4; ++q)
                    s += ybuf[(((q * 2 + igR) * 5 + mtR) * 64 + gR * 16 + cR) * 4 + iR];
                yr[d] = xs[R * ND + d] + s + b2[l * ND + d];
            }
            float m = 0.f;
#pragma unroll
            for (int d = 0; d < ND; ++d) m += yr[d];
            m *= (1.f / ND);
            float va = 0.f;
#pragma unroll
            for (int d = 0; d < ND; ++d) { float dv = yr[d] - m; va += dv * dv; }
            va *= (1.f / ND);
            float r = rsqrtf(va + EPSV);
#pragma unroll
            for (int d = 0; d < ND; ++d)
                xs[R * ND + d] = (yr[d] - m) * r * g2[l * ND + d] + be2[l * ND + d];
        }
        __syncthreads();
    }
    // ---------------- classification head + softmax ----------------
    if (tid < ITEMS) {
        float l0 = bfc[0], l1 = bfc[1];
#pragma unroll
        for (int v = 0; v < ROW; ++v) {
            float xv = xs[tid * ROW + v];
            l0 += Wfc[v] * xv;
            l1 += Wfc[ROW + v] * xv;
        }
        float mx = fmaxf(l0, l1);
        float e0 = __expf(l0 - mx), e1 = __expf(l1 - mx);
        float inv = 1.f / (e0 + e1);
        out[(size_t)(base + tid) * 2 + 0] = e0 * inv;
        out[(size_t)(base + tid) * 2 + 1] = e1 * inv;
    }
}

extern "C" void kernel_launch(void* const* d_in, const int* in_sizes, int n_in,
                              void* d_out, int out_size, void* d_ws, size_t ws_size,
                              hipStream_t stream) {
    (void)in_sizes; (void)n_in; (void)d_ws; (void)ws_size; (void)out_size;
    const float* x = (const float*)d_in[0];
    const float* Wq = (const float*)d_in[1];
    const float* bq = (const float*)d_in[2];
    const float* Wk = (const float*)d_in[3];
    const float* bk = (const float*)d_in[4];
    const float* Wv = (const float*)d_in[5];
    const float* bv = (const float*)d_in[6];
    const float* Wo = (const float*)d_in[7];
    const float* bo = (const float*)d_in[8];
    const float* W1 = (const float*)d_in[9];
    const float* b1 = (const float*)d_in[10];
    const float* W2 = (const float*)d_in[11];
    const float* b2 = (const float*)d_in[12];
    const float* g1 = (const float*)d_in[13];
    const float* be1 = (const float*)d_in[14];
    const float* g2 = (const float*)d_in[15];
    const float* be2 = (const float*)d_in[16];
    const float* Wfc = (const float*)d_in[17];
    const float* bfc = (const float*)d_in[18];
    float* out = (float*)d_out;

    const int npack = 3 * NL * NPAIR * 64;  // 49152
    hipLaunchKernelGGL(pack_kernel, dim3((npack + 255) / 256), dim3(256), 0, stream,
                       W1, b1, W2);
    hipLaunchKernelGGL(encoder_kernel, dim3(NBATCH / ITEMS), dim3(TPB), 0, stream,
                       x, Wq, bq, Wk, bk, Wv, bv, Wo, bo, b2, g1, be1, g2, be2,
                       Wfc, bfc, out);
}